// Round 7
// baseline (64.533 us; speedup 1.0000x reference)
//
#include <hip/hip_runtime.h>
#include <math.h>

#define NB     65536
#define NSP    26
#define NDN    13
#define EMBD   5
#define VOCAB  100000
#define NE     4
#define DIN    143
#define KPAD   160
#define H1     128
#define H2     64

typedef __attribute__((ext_vector_type(8))) short bf16x8;
typedef __attribute__((ext_vector_type(4))) float f32x4;

__device__ __forceinline__ unsigned short f2bf(float f) {
    unsigned int u = __float_as_uint(f);
    u = (u + 0x7fff + ((u >> 16) & 1)) >> 16;   // RNE
    return (unsigned short)u;
}

// pack two f32 -> two bf16 (RNE) in one VALU op
__device__ __forceinline__ unsigned cvtpk(float lo, float hi) {
    unsigned r;
    asm("v_cvt_pk_bf16_f32 %0, %1, %2" : "=v"(r) : "v"(lo), "v"(hi));
    return r;
}

// packed element counts (shorts); chunk = 512 shorts = 1KB = 64 lanes x 16B
#define E1 (4*8*5*512)    // w1p: [e][nt][s]   (per expert: 40 chunks = 20480 shorts)
#define E2 (4*4*4*512)    // w2p: [e][ot][s]   (per expert: 16 chunks =  8192 shorts)
#define E3 (5*512)        // gwp: [s]
#define NWE (E1+E2+E3)    // 117248
#define GBLKS 1024        // gather blocks (64 rows each)
#define PBLKS ((NWE+255)/256)

// ============================================================================
// FAST PATH
// ============================================================================
// Packed fragment layouts. Lane l = g*16+b (g=l>>4, b=l&15).
//   w1p chunk(e,nt,s): lane l holds W1^T[e][n=nt*16+b][k=32s+8g .. +8)
//   w2p chunk(e,ot,s): lane l holds W2^T[e][o=ot*16+b][k=32s+8g .. +8)
//   gwp chunk(s):      lane l holds G^T [row=b]       [k=32s+8g .. +8)
//   xg  chunk(t,s):    lane l holds x[row=t*16+b]     [k=32s+8g .. +8)

__global__ __launch_bounds__(256)
void gather_pack(const int*   __restrict__ sparse,
                 const float* __restrict__ dense,
                 const float* __restrict__ emb,
                 const float* __restrict__ W1,  const float* __restrict__ W2,
                 const float* __restrict__ gfW, const float* __restrict__ glW,
                 unsigned short* __restrict__ w1p, unsigned short* __restrict__ w2p,
                 unsigned short* __restrict__ gwp, unsigned short* __restrict__ xg)
{
    const int blk = blockIdx.x;
    const int tid = threadIdx.x;
    if (blk < GBLKS) {
        __shared__ int idxs[64 * NSP];                         // 6.5 KB
        __shared__ __align__(16) unsigned short xs[64][168];   // 21 KB, 336B stride
        const int row0 = blk * 64;

        for (int t = tid; t < 64 * NSP; t += 256)
            idxs[t] = sparse[row0 * NSP + t];
        for (int t = tid; t < 64 * NDN; t += 256) {
            int r = t / NDN, c = t - r * NDN;
            xs[r][c] = f2bf(dense[(row0 + r) * NDN + c]);
        }
        for (int t = tid; t < 64 * (KPAD - DIN); t += 256) {
            int r = t / (KPAD - DIN), c = DIN + (t - r * (KPAD - DIN));
            xs[r][c] = 0;
        }
        __syncthreads();
        for (int t = tid; t < 64 * NSP * EMBD; t += 256) {
            int f = t / (64 * EMBD);
            int rem = t - f * (64 * EMBD);
            int r = rem / EMBD, c = rem - r * EMBD;
            int idx = idxs[r * NSP + f];
            float v = emb[((size_t)f * VOCAB + idx) * EMBD + c];
            xs[r][NDN + f * EMBD + c] = f2bf(v);
        }
        __syncthreads();
        for (int v = tid; v < 4 * 5 * 64; v += 256) {
            int lo = v & 63, chunk = v >> 6;
            int s = chunk % 5, tl = chunk / 5;
            int b = lo & 15, g = lo >> 4;
            bf16x8 val = *(const bf16x8*)&xs[tl * 16 + b][32 * s + 8 * g];
            *(bf16x8*)(xg + ((size_t)((blk * 4 + tl) * 5 + s) * 64 + lo) * 8) = val;
        }
        return;
    }

    // ---- weight pack (tail blocks) ----
    int i = (blk - GBLKS) * 256 + tid;
    if (i < E1) {
        int j = i & 7, l = (i >> 3) & 63;
        int rest = i >> 9;
        int s = rest % 5; rest /= 5;
        int nt = rest & 7, e = rest >> 3;
        int b = l & 15, g = l >> 4;
        int k = 32 * s + 8 * g + j;
        int n = nt * 16 + b;
        w1p[i] = (k < DIN) ? f2bf(W1[(e * DIN + k) * H1 + n]) : (unsigned short)0;
        return;
    }
    i -= E1;
    if (i < E2) {
        int j = i & 7, l = (i >> 3) & 63;
        int rest = i >> 9;
        int s = rest & 3; rest >>= 2;
        int ot = rest & 3, e = rest >> 2;
        int b = l & 15, g = l >> 4;
        int k = 32 * s + 8 * g + j;
        int o = ot * 16 + b;
        w2p[i] = f2bf(W2[(e * H1 + k) * H2 + o]);
        return;
    }
    i -= E2;
    if (i < E3) {
        int j = i & 7, l = (i >> 3) & 63;
        int s = i >> 9;
        int b = l & 15, g = l >> 4;
        int k = 32 * s + 8 * g + j;
        float v = 0.f;
        if (k < DIN) {
            if (b < 4)      v = gfW[k * NE + b];
            else if (b < 8) v = glW[k * NE + (b - 4)];
        }
        gwp[i] = f2bf(v);
    }
}

// compute: 4 waves x 64 rows (R=4 row-tiles) = 256 rows/block, grid 256.
// Weight fragments are register-reused across 4 row-tiles -> per-CU weight
// LDS traffic halves vs R=2/8-wave, and each fragment feeds 4 independent
// MFMA chains (ILP instead of TLP). Epilogue uses v_cvt_pk_bf16_f32.
__global__ __launch_bounds__(256, 1)
void mmoe6(const unsigned short* __restrict__ xg,
           const unsigned short* __restrict__ w1p, const float* __restrict__ b1,
           const unsigned short* __restrict__ w2p, const float* __restrict__ b2,
           const unsigned short* __restrict__ gwp,
           const float* __restrict__ gfb, const float* __restrict__ glb,
           const float* __restrict__ fW,  const float* __restrict__ fb,
           const float* __restrict__ lW,  const float* __restrict__ lb,
           float* __restrict__ out)
{
    __shared__ __align__(16) unsigned short wlds[28672];   // 56 KB: w1(20480) | w2(8192)
    __shared__ __align__(16) char hsb[16 * 4096];          // 64 KB, swizzled h tiles
    __shared__ float gts[256][8];                          // 8 KB

    const int tid  = threadIdx.x;
    const int wid  = tid >> 6;                  // 0..3
    const int lane = tid & 63;
    const int b    = lane & 15;
    const int g    = lane >> 4;
    const int t0   = blockIdx.x * 16 + wid * 4; // 4 row-tiles per wave
    const int swz  = (b & 7) << 4;
    char* const hw = hsb + (wid * 4) * 4096 + b * 256;

    // ---- x fragments: 20 coalesced 1KB loads ----
    bf16x8 xf[4][5];
    #pragma unroll
    for (int rt = 0; rt < 4; ++rt)
        #pragma unroll
        for (int s = 0; s < 5; ++s)
            xf[rt][s] = *(const bf16x8*)(xg + ((size_t)((t0 + rt) * 5 + s) * 64 + lane) * 8);

    // ---- gates ----
    f32x4 ga[4];
    #pragma unroll
    for (int rt = 0; rt < 4; ++rt) ga[rt] = (f32x4){0.f, 0.f, 0.f, 0.f};
    #pragma unroll
    for (int s = 0; s < 5; ++s) {
        bf16x8 af = *(const bf16x8*)(gwp + (size_t)(s * 64 + lane) * 8);
        #pragma unroll
        for (int rt = 0; rt < 4; ++rt)
            ga[rt] = __builtin_amdgcn_mfma_f32_16x16x32_bf16(af, xf[rt][s], ga[rt], 0, 0, 0);
    }
    if (g < 2) {
        const float4 bias = *(const float4*)(g ? glb : gfb);
        #pragma unroll
        for (int rt = 0; rt < 4; ++rt) {
            float l0 = ga[rt][0] + bias.x, l1 = ga[rt][1] + bias.y;
            float l2 = ga[rt][2] + bias.z, l3 = ga[rt][3] + bias.w;
            float m = fmaxf(fmaxf(l0, l1), fmaxf(l2, l3));
            float e0 = expf(l0 - m), e1 = expf(l1 - m), e2 = expf(l2 - m), e3 = expf(l3 - m);
            float inv = 1.f / (e0 + e1 + e2 + e3);
            float4 gv; gv.x = e0 * inv; gv.y = e1 * inv; gv.z = e2 * inv; gv.w = e3 * inv;
            *(float4*)&gts[wid * 64 + rt * 16 + b][g * 4] = gv;
        }
    }

    // ---- expert loop ----
    float vf[4] = {0.f, 0.f, 0.f, 0.f}, vl[4] = {0.f, 0.f, 0.f, 0.f};
    for (int e = 0; e < NE; ++e) {
        // stage this expert's 56 KB into LDS (coalesced, linear copy)
        __syncthreads();   // all waves done reading wlds from previous expert
        #pragma unroll
        for (int i = 0; i < 10; ++i) {
            int v = tid + i * 256;
            *(bf16x8*)(wlds + v * 8) = *(const bf16x8*)(w1p + (size_t)e * 20480 + v * 8);
        }
        #pragma unroll
        for (int i = 0; i < 4; ++i) {
            int v = tid + i * 256;
            *(bf16x8*)(wlds + 20480 + v * 8) = *(const bf16x8*)(w2p + (size_t)e * 8192 + v * 8);
        }
        __syncthreads();

        // Stage A: h = relu(x @ W1[e]^T + b1); W1 frags from LDS, h -> wave-private LDS
        #pragma unroll
        for (int nt = 0; nt < 8; ++nt) {
            bf16x8 wv[5];
            #pragma unroll
            for (int s = 0; s < 5; ++s)
                wv[s] = *(const bf16x8*)(wlds + ((nt * 5 + s) * 64 + lane) * 8);
            f32x4 acc[4];
            #pragma unroll
            for (int rt = 0; rt < 4; ++rt) acc[rt] = (f32x4){0.f, 0.f, 0.f, 0.f};
            #pragma unroll
            for (int s = 0; s < 5; ++s)
                #pragma unroll
                for (int rt = 0; rt < 4; ++rt)
                    acc[rt] = __builtin_amdgcn_mfma_f32_16x16x32_bf16(wv[s], xf[rt][s], acc[rt], 0, 0, 0);
            const float4 b1v = *(const float4*)(b1 + e * H1 + nt * 16 + 4 * g);
            #pragma unroll
            for (int rt = 0; rt < 4; ++rt) {
                uint2 hv;
                hv.x = cvtpk(fmaxf(acc[rt][0] + b1v.x, 0.f), fmaxf(acc[rt][1] + b1v.y, 0.f));
                hv.y = cvtpk(fmaxf(acc[rt][2] + b1v.z, 0.f), fmaxf(acc[rt][3] + b1v.w, 0.f));
                *(uint2*)(hw + rt * 4096 + ((nt * 32 + g * 8) ^ swz)) = hv;
            }
        }

        // Stage B: expert_out = relu(h @ W2[e]^T + b2); fold gates + head weights
        bf16x8 hf[4][4];
        #pragma unroll
        for (int rt = 0; rt < 4; ++rt)
            #pragma unroll
            for (int s = 0; s < 4; ++s)
                hf[rt][s] = *(const bf16x8*)(hw + rt * 4096 + ((s * 64 + g * 16) ^ swz));

        float gfv[4], glv[4];
        #pragma unroll
        for (int rt = 0; rt < 4; ++rt) {
            gfv[rt] = gts[wid * 64 + rt * 16 + b][e];
            glv[rt] = gts[wid * 64 + rt * 16 + b][4 + e];
        }

        #pragma unroll
        for (int ot = 0; ot < 4; ++ot) {
            bf16x8 wv2[4];
            #pragma unroll
            for (int s = 0; s < 4; ++s)
                wv2[s] = *(const bf16x8*)(wlds + 20480 + ((ot * 4 + s) * 64 + lane) * 8);
            f32x4 c[4];
            #pragma unroll
            for (int rt = 0; rt < 4; ++rt) c[rt] = (f32x4){0.f, 0.f, 0.f, 0.f};
            #pragma unroll
            for (int s = 0; s < 4; ++s)
                #pragma unroll
                for (int rt = 0; rt < 4; ++rt)
                    c[rt] = __builtin_amdgcn_mfma_f32_16x16x32_bf16(wv2[s], hf[rt][s], c[rt], 0, 0, 0);
            const float4 b2v = *(const float4*)(b2 + e * H2 + ot * 16 + 4 * g);
            const float4 fwv = *(const float4*)(fW + ot * 16 + 4 * g);
            const float4 lwv = *(const float4*)(lW + ot * 16 + 4 * g);
            #pragma unroll
            for (int rt = 0; rt < 4; ++rt) {
                float o0 = fmaxf(c[rt][0] + b2v.x, 0.f), o1 = fmaxf(c[rt][1] + b2v.y, 0.f);
                float o2 = fmaxf(c[rt][2] + b2v.z, 0.f), o3 = fmaxf(c[rt][3] + b2v.w, 0.f);
                vf[rt] += gfv[rt] * (o0 * fwv.x + o1 * fwv.y + o2 * fwv.z + o3 * fwv.w);
                vl[rt] += glv[rt] * (o0 * lwv.x + o1 * lwv.y + o2 * lwv.z + o3 * lwv.w);
            }
        }
    }

    // ---- heads ----
    #pragma unroll
    for (int rt = 0; rt < 4; ++rt) {
        float f = vf[rt], l = vl[rt];
        f += __shfl_xor(f, 16); f += __shfl_xor(f, 32);
        l += __shfl_xor(l, 16); l += __shfl_xor(l, 32);
        if (g == 0) {
            int r = (t0 + rt) * 16 + b;
            out[r]      = 1.f / (1.f + expf(-(f + fb[0])));
            out[NB + r] = 1.f / (1.f + expf(-(l + lb[0])));
        }
    }
}

// ============================================================================
// FALLBACK PATH (used only if ws_size < 21.2 MB)
// ============================================================================

__global__ __launch_bounds__(256)
void preproc(const float* __restrict__ W1, const float* __restrict__ W2,
             const float* __restrict__ gfW, const float* __restrict__ glW,
             unsigned short* __restrict__ w1t, unsigned short* __restrict__ w2t,
             unsigned short* __restrict__ gwc)
{
    int i = blockIdx.x * 256 + threadIdx.x;
    if (i < 4*128*160) {
        int k = i % KPAD;
        int n = (i / KPAD) & (H1 - 1);
        int e = i / (KPAD * H1);
        w1t[i] = (k < DIN) ? f2bf(W1[(e * DIN + k) * H1 + n]) : (unsigned short)0;
    } else if (i < 4*128*160 + 4*64*128) {
        int j = i - 4*128*160;
        int k = j & (H1 - 1);
        int o = (j >> 7) & (H2 - 1);
        int e = j >> 13;
        w2t[j] = f2bf(W2[(e * H1 + k) * H2 + o]);
    } else if (i < 4*128*160 + 4*64*128 + 16*160) {
        int j = i - (4*128*160 + 4*64*128);
        int k = j % KPAD;
        int r = j / KPAD;
        float v = 0.f;
        if (k < DIN) {
            if (r < 4)      v = gfW[k * NE + r];
            else if (r < 8) v = glW[k * NE + (r - 4)];
        }
        gwc[j] = f2bf(v);
    }
}

__global__ __launch_bounds__(256)
void mmoe_mfma(const int*   __restrict__ sparse,
               const float* __restrict__ dense,
               const float* __restrict__ emb,
               const unsigned short* __restrict__ w1t,
               const float* __restrict__ b1,
               const unsigned short* __restrict__ w2t,
               const float* __restrict__ b2,
               const unsigned short* __restrict__ gwc,
               const float* __restrict__ gfb, const float* __restrict__ glb,
               const float* __restrict__ fW,  const float* __restrict__ fb,
               const float* __restrict__ lW,  const float* __restrict__ lb,
               float* __restrict__ out)
{
    __shared__ __align__(16) unsigned short xs[64][KPAD];
    __shared__ __align__(16) unsigned short hs[64][136];
    __shared__ __align__(16) float gts[64][8];

    const int tid   = threadIdx.x;
    const int wid   = tid >> 6;
    const int lane  = tid & 63;
    const int b     = lane & 15;
    const int g     = lane >> 4;
    const int rbase = wid * 16;
    const int grow0 = blockIdx.x * 64 + rbase;

    for (int t = lane; t < 16 * NDN; t += 64) {
        int r = t & 15, d = t >> 4;
        xs[rbase + r][d] = f2bf(dense[(grow0 + r) * NDN + d]);
    }
    for (int t = lane; t < 16 * (KPAD - DIN); t += 64) {
        int r = t & 15, d = DIN + (t >> 4);
        xs[rbase + r][d] = 0;
    }
    for (int t = lane; t < 16 * NSP; t += 64) {
        int r = t & 15, f = t >> 4;
        int idx = sparse[(grow0 + r) * NSP + f];
        const float* ep = emb + (f * VOCAB + idx) * EMBD;
        int c0 = NDN + EMBD * f;
        #pragma unroll
        for (int c = 0; c < EMBD; ++c)
            xs[rbase + r][c0 + c] = f2bf(ep[c]);
    }

    bf16x8 xf[5];
    #pragma unroll
    for (int s = 0; s < 5; ++s)
        xf[s] = *(const bf16x8*)&xs[rbase + b][32 * s + 8 * g];

    f32x4 ga = {0.f, 0.f, 0.f, 0.f};
    #pragma unroll
    for (int s = 0; s < 5; ++s) {
        bf16x8 af = *(const bf16x8*)(gwc + b * KPAD + 32 * s + 8 * g);
        ga = __builtin_amdgcn_mfma_f32_16x16x32_bf16(af, xf[s], ga, 0, 0, 0);
    }
    if (g < 2) {
        const float4 bias = *(const float4*)(g ? glb : gfb);
        float l0 = ga[0] + bias.x, l1 = ga[1] + bias.y;
        float l2 = ga[2] + bias.z, l3 = ga[3] + bias.w;
        float m = fmaxf(fmaxf(l0, l1), fmaxf(l2, l3));
        float e0 = expf(l0 - m), e1 = expf(l1 - m), e2 = expf(l2 - m), e3 = expf(l3 - m);
        float inv = 1.f / (e0 + e1 + e2 + e3);
        float4 gv; gv.x = e0 * inv; gv.y = e1 * inv; gv.z = e2 * inv; gv.w = e3 * inv;
        *(float4*)&gts[rbase + b][g * 4] = gv;
    }

    float vf = 0.f, vl = 0.f;
    for (int e = 0; e < NE; ++e) {
        const unsigned short* w1e = w1t + e * (H1 * KPAD);
        #pragma unroll
        for (int nt = 0; nt < 8; ++nt) {
            f32x4 acc = {0.f, 0.f, 0.f, 0.f};
            #pragma unroll
            for (int s = 0; s < 5; ++s) {
                bf16x8 af = *(const bf16x8*)(w1e + (nt * 16 + b) * KPAD + 32 * s + 8 * g);
                acc = __builtin_amdgcn_mfma_f32_16x16x32_bf16(af, xf[s], acc, 0, 0, 0);
            }
            const float4 b1v = *(const float4*)(b1 + e * H1 + nt * 16 + 4 * g);
            unsigned lo = (unsigned)f2bf(fmaxf(acc[0] + b1v.x, 0.f)) |
                          ((unsigned)f2bf(fmaxf(acc[1] + b1v.y, 0.f)) << 16);
            unsigned hi = (unsigned)f2bf(fmaxf(acc[2] + b1v.z, 0.f)) |
                          ((unsigned)f2bf(fmaxf(acc[3] + b1v.w, 0.f)) << 16);
            uint2 hv; hv.x = lo; hv.y = hi;
            *(uint2*)&hs[rbase + b][nt * 16 + 4 * g] = hv;
        }

        bf16x8 hf[4];
        #pragma unroll
        for (int s = 0; s < 4; ++s)
            hf[s] = *(const bf16x8*)&hs[rbase + b][32 * s + 8 * g];

        float gf = gts[rbase + b][e];
        float gl = gts[rbase + b][4 + e];
        const unsigned short* w2e = w2t + e * (H2 * H1);
        #pragma unroll
        for (int ot = 0; ot < 4; ++ot) {
            f32x4 acc = {0.f, 0.f, 0.f, 0.f};
            #pragma unroll
            for (int s = 0; s < 4; ++s) {
                bf16x8 af = *(const bf16x8*)(w2e + (ot * 16 + b) * H1 + 32 * s + 8 * g);
                acc = __builtin_amdgcn_mfma_f32_16x16x32_bf16(af, hf[s], acc, 0, 0, 0);
            }
            const float4 b2v = *(const float4*)(b2 + e * H2 + ot * 16 + 4 * g);
            const float4 fwv = *(const float4*)(fW + ot * 16 + 4 * g);
            const float4 lwv = *(const float4*)(lW + ot * 16 + 4 * g);
            float o0 = fmaxf(acc[0] + b2v.x, 0.f);
            float o1 = fmaxf(acc[1] + b2v.y, 0.f);
            float o2 = fmaxf(acc[2] + b2v.z, 0.f);
            float o3 = fmaxf(acc[3] + b2v.w, 0.f);
            vf += gf * (o0 * fwv.x + o1 * fwv.y + o2 * fwv.z + o3 * fwv.w);
            vl += gl * (o0 * lwv.x + o1 * lwv.y + o2 * lwv.z + o3 * lwv.w);
        }
    }

    vf += __shfl_xor(vf, 16); vf += __shfl_xor(vf, 32);
    vl += __shfl_xor(vl, 16); vl += __shfl_xor(vl, 32);
    if (g == 0) {
        int r = grow0 + b;
        out[r]      = 1.f / (1.f + expf(-(vf + fb[0])));
        out[NB + r] = 1.f / (1.f + expf(-(vl + lb[0])));
    }
}

// ============================================================================

extern "C" void kernel_launch(void* const* d_in, const int* in_sizes, int n_in,
                              void* d_out, int out_size, void* d_ws, size_t ws_size,
                              hipStream_t stream) {
    const int*   sparse = (const int*)  d_in[0];
    const float* dense  = (const float*)d_in[1];
    const float* emb    = (const float*)d_in[2];
    const float* W1     = (const float*)d_in[3];
    const float* b1     = (const float*)d_in[4];
    const float* W2     = (const float*)d_in[5];
    const float* b2     = (const float*)d_in[6];
    const float* gfW    = (const float*)d_in[7];
    const float* gfb    = (const float*)d_in[8];
    const float* glW    = (const float*)d_in[9];
    const float* glb    = (const float*)d_in[10];
    const float* fW     = (const float*)d_in[11];
    const float* fb     = (const float*)d_in[12];
    const float* lW     = (const float*)d_in[13];
    const float* lb     = (const float*)d_in[14];

    const size_t XG_BYTES = (size_t)NB * KPAD * 2;            // 20,971,520
    const size_t NEED = XG_BYTES + (size_t)NWE * 2;           // ~21.2 MB

    if (ws_size >= NEED) {
        unsigned short* xg  = (unsigned short*)d_ws;
        unsigned short* w1p = (unsigned short*)((char*)d_ws + XG_BYTES);
        unsigned short* w2p = (unsigned short*)((char*)d_ws + XG_BYTES + (size_t)E1 * 2);
        unsigned short* gwp = (unsigned short*)((char*)d_ws + XG_BYTES + (size_t)(E1 + E2) * 2);

        gather_pack<<<GBLKS + PBLKS, 256, 0, stream>>>(
            sparse, dense, emb, W1, W2, gfW, glW, w1p, w2p, gwp, xg);
        mmoe6<<<NB / 256, 256, 0, stream>>>(xg, w1p, b1, w2p, b2, gwp,
                                            gfb, glb, fW, fb, lW, lb,
                                            (float*)d_out);
    } else {
        unsigned short* w1t = (unsigned short*)d_ws;
        unsigned short* w2t = (unsigned short*)((char*)d_ws + 163840);
        unsigned short* gwc = (unsigned short*)((char*)d_ws + 229376);

        int tot = 4*128*160 + 4*64*128 + 16*160;
        preproc<<<(tot + 255) / 256, 256, 0, stream>>>(W1, W2, gfW, glW, w1t, w2t, gwc);
        mmoe_mfma<<<NB / 64, 256, 0, stream>>>(sparse, dense, emb,
                                               w1t, b1, w2t, b2, gwc,
                                               gfb, glb, fW, fb, lW, lb,
                                               (float*)d_out);
    }
}

// Round 8
// 58.580 us; speedup vs baseline: 1.1016x; 1.1016x over previous
//
#include <hip/hip_runtime.h>
#include <math.h>

#define NB     65536
#define NSP    26
#define NDN    13
#define EMBD   5
#define VOCAB  100000
#define NE     4
#define DIN    143
#define KPAD   160
#define H1     128
#define H2     64

typedef __attribute__((ext_vector_type(8))) short bf16x8;
typedef __attribute__((ext_vector_type(4))) float f32x4;

__device__ __forceinline__ unsigned short f2bf(float f) {
    unsigned int u = __float_as_uint(f);
    u = (u + 0x7fff + ((u >> 16) & 1)) >> 16;   // RNE
    return (unsigned short)u;
}

__device__ __forceinline__ unsigned cvtpk(float lo, float hi) {
    unsigned r;
    asm("v_cvt_pk_bf16_f32 %0, %1, %2" : "=v"(r) : "v"(lo), "v"(hi));
    return r;
}

// packed element counts (shorts); chunk = 512 shorts = 1KB = 64 lanes x 16B
#define E1 (4*8*5*512)    // w1p: [e][nt][s]   (per expert 20480 shorts = 40 KB)
#define E2 (4*4*4*512)    // w2p: [e][ot][s]   (per expert  8192 shorts = 16 KB)
#define E3 (5*512)        // gwp: [s]
#define NWE (E1+E2+E3)
#define GBLKS 1024
#define PBLKS ((NWE+255)/256)

// ============================================================================
// FAST PATH
// ============================================================================

__global__ __launch_bounds__(256)
void gather_pack(const int*   __restrict__ sparse,
                 const float* __restrict__ dense,
                 const float* __restrict__ emb,
                 const float* __restrict__ W1,  const float* __restrict__ W2,
                 const float* __restrict__ gfW, const float* __restrict__ glW,
                 unsigned short* __restrict__ w1p, unsigned short* __restrict__ w2p,
                 unsigned short* __restrict__ gwp, unsigned short* __restrict__ xg)
{
    const int blk = blockIdx.x;
    const int tid = threadIdx.x;
    if (blk < GBLKS) {
        __shared__ int idxs[64 * NSP];
        __shared__ __align__(16) unsigned short xs[64][168];
        const int row0 = blk * 64;

        for (int t = tid; t < 64 * NSP; t += 256)
            idxs[t] = sparse[row0 * NSP + t];
        for (int t = tid; t < 64 * NDN; t += 256) {
            int r = t / NDN, c = t - r * NDN;
            xs[r][c] = f2bf(dense[(row0 + r) * NDN + c]);
        }
        for (int t = tid; t < 64 * (KPAD - DIN); t += 256) {
            int r = t / (KPAD - DIN), c = DIN + (t - r * (KPAD - DIN));
            xs[r][c] = 0;
        }
        __syncthreads();
        for (int t = tid; t < 64 * NSP * EMBD; t += 256) {
            int f = t / (64 * EMBD);
            int rem = t - f * (64 * EMBD);
            int r = rem / EMBD, c = rem - r * EMBD;
            int idx = idxs[r * NSP + f];
            float v = emb[((size_t)f * VOCAB + idx) * EMBD + c];
            xs[r][NDN + f * EMBD + c] = f2bf(v);
        }
        __syncthreads();
        for (int v = tid; v < 4 * 5 * 64; v += 256) {
            int lo = v & 63, chunk = v >> 6;
            int s = chunk % 5, tl = chunk / 5;
            int b = lo & 15, g = lo >> 4;
            bf16x8 val = *(const bf16x8*)&xs[tl * 16 + b][32 * s + 8 * g];
            *(bf16x8*)(xg + ((size_t)((blk * 4 + tl) * 5 + s) * 64 + lo) * 8) = val;
        }
        return;
    }

    int i = (blk - GBLKS) * 256 + tid;
    if (i < E1) {
        int j = i & 7, l = (i >> 3) & 63;
        int rest = i >> 9;
        int s = rest % 5; rest /= 5;
        int nt = rest & 7, e = rest >> 3;
        int b = l & 15, g = l >> 4;
        int k = 32 * s + 8 * g + j;
        int n = nt * 16 + b;
        w1p[i] = (k < DIN) ? f2bf(W1[(e * DIN + k) * H1 + n]) : (unsigned short)0;
        return;
    }
    i -= E1;
    if (i < E2) {
        int j = i & 7, l = (i >> 3) & 63;
        int rest = i >> 9;
        int s = rest & 3; rest >>= 2;
        int ot = rest & 3, e = rest >> 2;
        int b = l & 15, g = l >> 4;
        int k = 32 * s + 8 * g + j;
        int o = ot * 16 + b;
        w2p[i] = f2bf(W2[(e * H1 + k) * H2 + o]);
        return;
    }
    i -= E2;
    if (i < E3) {
        int j = i & 7, l = (i >> 3) & 63;
        int s = i >> 9;
        int b = l & 15, g = l >> 4;
        int k = 32 * s + 8 * g + j;
        float v = 0.f;
        if (k < DIN) {
            if (b < 4)      v = gfW[k * NE + b];
            else if (b < 8) v = glW[k * NE + (b - 4)];
        }
        gwp[i] = f2bf(v);
    }
}

// compute: 4 waves x 32 rows (R=2) = 128 rows/block, grid 512 = 2 blocks/CU.
// Two independent 4-wave barrier groups per CU fill each other's staging and
// barrier-drain stalls. Next-expert weights are prefetched into registers
// during compute (T14): staging inside the barrier window is pure ds_write.
// LDS 76 KB: wlds 56K | hs 16K (nt-halved slices) | gts 4K.
__global__ __launch_bounds__(256, 2)
void mmoe7(const unsigned short* __restrict__ xg,
           const unsigned short* __restrict__ w1p, const float* __restrict__ b1,
           const unsigned short* __restrict__ w2p, const float* __restrict__ b2,
           const unsigned short* __restrict__ gwp,
           const float* __restrict__ gfb, const float* __restrict__ glb,
           const float* __restrict__ fW,  const float* __restrict__ fb,
           const float* __restrict__ lW,  const float* __restrict__ lb,
           float* __restrict__ out)
{
    __shared__ __align__(16) char wlds[57344];   // 40K w1 | 16K w2
    __shared__ __align__(16) char hsb[16384];    // 4 waves x [2rt][16][64] bf16
    __shared__ float gts[128][8];

    const int tid  = threadIdx.x;
    const int wid  = tid >> 6;
    const int lane = tid & 63;
    const int b    = lane & 15;
    const int g    = lane >> 4;
    const int t0   = blockIdx.x * 8 + wid * 2;   // 2 row-tiles per wave
    const int swz  = (b & 7) << 4;
    char* const hw = hsb + wid * 4096 + b * 128;

    // ---- x fragments ----
    bf16x8 xf[2][5];
    #pragma unroll
    for (int rt = 0; rt < 2; ++rt)
        #pragma unroll
        for (int s = 0; s < 5; ++s)
            xf[rt][s] = *(const bf16x8*)(xg + ((size_t)((t0 + rt) * 5 + s) * 64 + lane) * 8);

    // ---- prefetch expert 0 weights into registers ----
    bf16x8 pw1[10], pw2[4];
    #pragma unroll
    for (int i = 0; i < 10; ++i)
        pw1[i] = *(const bf16x8*)(w1p + (size_t)(tid + i * 256) * 8);
    #pragma unroll
    for (int i = 0; i < 4; ++i)
        pw2[i] = *(const bf16x8*)(w2p + (size_t)(tid + i * 256) * 8);

    // ---- gates ----
    f32x4 ga[2];
    ga[0] = (f32x4){0.f, 0.f, 0.f, 0.f};
    ga[1] = (f32x4){0.f, 0.f, 0.f, 0.f};
    #pragma unroll
    for (int s = 0; s < 5; ++s) {
        bf16x8 af = *(const bf16x8*)(gwp + (size_t)(s * 64 + lane) * 8);
        ga[0] = __builtin_amdgcn_mfma_f32_16x16x32_bf16(af, xf[0][s], ga[0], 0, 0, 0);
        ga[1] = __builtin_amdgcn_mfma_f32_16x16x32_bf16(af, xf[1][s], ga[1], 0, 0, 0);
    }
    if (g < 2) {
        const float4 bias = *(const float4*)(g ? glb : gfb);
        #pragma unroll
        for (int rt = 0; rt < 2; ++rt) {
            float l0 = ga[rt][0] + bias.x, l1 = ga[rt][1] + bias.y;
            float l2 = ga[rt][2] + bias.z, l3 = ga[rt][3] + bias.w;
            float m = fmaxf(fmaxf(l0, l1), fmaxf(l2, l3));
            float e0 = expf(l0 - m), e1 = expf(l1 - m), e2 = expf(l2 - m), e3 = expf(l3 - m);
            float inv = 1.f / (e0 + e1 + e2 + e3);
            float4 gv; gv.x = e0 * inv; gv.y = e1 * inv; gv.z = e2 * inv; gv.w = e3 * inv;
            *(float4*)&gts[wid * 32 + rt * 16 + b][g * 4] = gv;
        }
    }

    // ---- expert loop ----
    float vf[2] = {0.f, 0.f}, vl[2] = {0.f, 0.f};
    for (int e = 0; e < NE; ++e) {
        __syncthreads();   // all 4 waves done reading wlds of expert e-1
        #pragma unroll
        for (int i = 0; i < 10; ++i)
            *(bf16x8*)(wlds + (tid + i * 256) * 16) = pw1[i];
        #pragma unroll
        for (int i = 0; i < 4; ++i)
            *(bf16x8*)(wlds + 40960 + (tid + i * 256) * 16) = pw2[i];
        if (e < 3) {   // prefetch next expert during this expert's compute
            #pragma unroll
            for (int i = 0; i < 10; ++i)
                pw1[i] = *(const bf16x8*)(w1p + (size_t)(e + 1) * 20480 + (size_t)(tid + i * 256) * 8);
            #pragma unroll
            for (int i = 0; i < 4; ++i)
                pw2[i] = *(const bf16x8*)(w2p + (size_t)(e + 1) * 8192 + (size_t)(tid + i * 256) * 8);
        }
        __syncthreads();

        f32x4 c[2][4];
        #pragma unroll
        for (int rt = 0; rt < 2; ++rt)
            #pragma unroll
            for (int ot = 0; ot < 4; ++ot)
                c[rt][ot] = (f32x4){0.f, 0.f, 0.f, 0.f};

        #pragma unroll
        for (int h = 0; h < 2; ++h) {
            // Stage A half: nt = h*4 .. h*4+3 -> hs slice cols 0..63 (= k 64h..64h+63 of h-vec)
            #pragma unroll
            for (int nl = 0; nl < 4; ++nl) {
                const int nt = h * 4 + nl;
                bf16x8 wv[5];
                #pragma unroll
                for (int s = 0; s < 5; ++s)
                    wv[s] = *(const bf16x8*)(wlds + ((nt * 5 + s) * 64 + lane) * 16);
                f32x4 acc[2];
                acc[0] = (f32x4){0.f, 0.f, 0.f, 0.f};
                acc[1] = (f32x4){0.f, 0.f, 0.f, 0.f};
                #pragma unroll
                for (int s = 0; s < 5; ++s) {
                    acc[0] = __builtin_amdgcn_mfma_f32_16x16x32_bf16(wv[s], xf[0][s], acc[0], 0, 0, 0);
                    acc[1] = __builtin_amdgcn_mfma_f32_16x16x32_bf16(wv[s], xf[1][s], acc[1], 0, 0, 0);
                }
                const float4 b1v = *(const float4*)(b1 + e * H1 + nt * 16 + 4 * g);
                #pragma unroll
                for (int rt = 0; rt < 2; ++rt) {
                    uint2 hv;
                    hv.x = cvtpk(fmaxf(acc[rt][0] + b1v.x, 0.f), fmaxf(acc[rt][1] + b1v.y, 0.f));
                    hv.y = cvtpk(fmaxf(acc[rt][2] + b1v.z, 0.f), fmaxf(acc[rt][3] + b1v.w, 0.f));
                    *(uint2*)(hw + rt * 2048 + ((nl * 32 + g * 8) ^ swz)) = hv;
                }
            }
            // Stage B half: accumulate k-groups s = 2h, 2h+1 into c
            bf16x8 hf[2][2];
            #pragma unroll
            for (int sl = 0; sl < 2; ++sl)
                #pragma unroll
                for (int rt = 0; rt < 2; ++rt)
                    hf[sl][rt] = *(const bf16x8*)(hw + rt * 2048 + ((sl * 64 + g * 16) ^ swz));
            #pragma unroll
            for (int ot = 0; ot < 4; ++ot) {
                #pragma unroll
                for (int sl = 0; sl < 2; ++sl) {
                    bf16x8 wv2 = *(const bf16x8*)(wlds + 40960 + ((ot * 4 + h * 2 + sl) * 64 + lane) * 16);
                    c[0][ot] = __builtin_amdgcn_mfma_f32_16x16x32_bf16(wv2, hf[sl][0], c[0][ot], 0, 0, 0);
                    c[1][ot] = __builtin_amdgcn_mfma_f32_16x16x32_bf16(wv2, hf[sl][1], c[1][ot], 0, 0, 0);
                }
            }
        }

        // fold gates + head weights
        float gfv[2], glv[2];
        #pragma unroll
        for (int rt = 0; rt < 2; ++rt) {
            gfv[rt] = gts[wid * 32 + rt * 16 + b][e];
            glv[rt] = gts[wid * 32 + rt * 16 + b][4 + e];
        }
        #pragma unroll
        for (int ot = 0; ot < 4; ++ot) {
            const float4 b2v = *(const float4*)(b2 + e * H2 + ot * 16 + 4 * g);
            const float4 fwv = *(const float4*)(fW + ot * 16 + 4 * g);
            const float4 lwv = *(const float4*)(lW + ot * 16 + 4 * g);
            #pragma unroll
            for (int rt = 0; rt < 2; ++rt) {
                float o0 = fmaxf(c[rt][ot][0] + b2v.x, 0.f), o1 = fmaxf(c[rt][ot][1] + b2v.y, 0.f);
                float o2 = fmaxf(c[rt][ot][2] + b2v.z, 0.f), o3 = fmaxf(c[rt][ot][3] + b2v.w, 0.f);
                vf[rt] += gfv[rt] * (o0 * fwv.x + o1 * fwv.y + o2 * fwv.z + o3 * fwv.w);
                vl[rt] += glv[rt] * (o0 * lwv.x + o1 * lwv.y + o2 * lwv.z + o3 * lwv.w);
            }
        }
    }

    // ---- heads ----
    #pragma unroll
    for (int rt = 0; rt < 2; ++rt) {
        float f = vf[rt], l = vl[rt];
        f += __shfl_xor(f, 16); f += __shfl_xor(f, 32);
        l += __shfl_xor(l, 16); l += __shfl_xor(l, 32);
        if (g == 0) {
            int r = (t0 + rt) * 16 + b;
            out[r]      = 1.f / (1.f + expf(-(f + fb[0])));
            out[NB + r] = 1.f / (1.f + expf(-(l + lb[0])));
        }
    }
}

// ============================================================================
// FALLBACK PATH (used only if ws_size < 21.2 MB)
// ============================================================================

__global__ __launch_bounds__(256)
void preproc(const float* __restrict__ W1, const float* __restrict__ W2,
             const float* __restrict__ gfW, const float* __restrict__ glW,
             unsigned short* __restrict__ w1t, unsigned short* __restrict__ w2t,
             unsigned short* __restrict__ gwc)
{
    int i = blockIdx.x * 256 + threadIdx.x;
    if (i < 4*128*160) {
        int k = i % KPAD;
        int n = (i / KPAD) & (H1 - 1);
        int e = i / (KPAD * H1);
        w1t[i] = (k < DIN) ? f2bf(W1[(e * DIN + k) * H1 + n]) : (unsigned short)0;
    } else if (i < 4*128*160 + 4*64*128) {
        int j = i - 4*128*160;
        int k = j & (H1 - 1);
        int o = (j >> 7) & (H2 - 1);
        int e = j >> 13;
        w2t[j] = f2bf(W2[(e * H1 + k) * H2 + o]);
    } else if (i < 4*128*160 + 4*64*128 + 16*160) {
        int j = i - (4*128*160 + 4*64*128);
        int k = j % KPAD;
        int r = j / KPAD;
        float v = 0.f;
        if (k < DIN) {
            if (r < 4)      v = gfW[k * NE + r];
            else if (r < 8) v = glW[k * NE + (r - 4)];
        }
        gwc[j] = f2bf(v);
    }
}

__global__ __launch_bounds__(256)
void mmoe_mfma(const int*   __restrict__ sparse,
               const float* __restrict__ dense,
               const float* __restrict__ emb,
               const unsigned short* __restrict__ w1t,
               const float* __restrict__ b1,
               const unsigned short* __restrict__ w2t,
               const float* __restrict__ b2,
               const unsigned short* __restrict__ gwc,
               const float* __restrict__ gfb, const float* __restrict__ glb,
               const float* __restrict__ fW,  const float* __restrict__ fb,
               const float* __restrict__ lW,  const float* __restrict__ lb,
               float* __restrict__ out)
{
    __shared__ __align__(16) unsigned short xs[64][KPAD];
    __shared__ __align__(16) unsigned short hs[64][136];
    __shared__ __align__(16) float gts[64][8];

    const int tid   = threadIdx.x;
    const int wid   = tid >> 6;
    const int lane  = tid & 63;
    const int b     = lane & 15;
    const int g     = lane >> 4;
    const int rbase = wid * 16;
    const int grow0 = blockIdx.x * 64 + rbase;

    for (int t = lane; t < 16 * NDN; t += 64) {
        int r = t & 15, d = t >> 4;
        xs[rbase + r][d] = f2bf(dense[(grow0 + r) * NDN + d]);
    }
    for (int t = lane; t < 16 * (KPAD - DIN); t += 64) {
        int r = t & 15, d = DIN + (t >> 4);
        xs[rbase + r][d] = 0;
    }
    for (int t = lane; t < 16 * NSP; t += 64) {
        int r = t & 15, f = t >> 4;
        int idx = sparse[(grow0 + r) * NSP + f];
        const float* ep = emb + (f * VOCAB + idx) * EMBD;
        int c0 = NDN + EMBD * f;
        #pragma unroll
        for (int c = 0; c < EMBD; ++c)
            xs[rbase + r][c0 + c] = f2bf(ep[c]);
    }

    bf16x8 xf[5];
    #pragma unroll
    for (int s = 0; s < 5; ++s)
        xf[s] = *(const bf16x8*)&xs[rbase + b][32 * s + 8 * g];

    f32x4 ga = {0.f, 0.f, 0.f, 0.f};
    #pragma unroll
    for (int s = 0; s < 5; ++s) {
        bf16x8 af = *(const bf16x8*)(gwc + b * KPAD + 32 * s + 8 * g);
        ga = __builtin_amdgcn_mfma_f32_16x16x32_bf16(af, xf[s], ga, 0, 0, 0);
    }
    if (g < 2) {
        const float4 bias = *(const float4*)(g ? glb : gfb);
        float l0 = ga[0] + bias.x, l1 = ga[1] + bias.y;
        float l2 = ga[2] + bias.z, l3 = ga[3] + bias.w;
        float m = fmaxf(fmaxf(l0, l1), fmaxf(l2, l3));
        float e0 = expf(l0 - m), e1 = expf(l1 - m), e2 = expf(l2 - m), e3 = expf(l3 - m);
        float inv = 1.f / (e0 + e1 + e2 + e3);
        float4 gv; gv.x = e0 * inv; gv.y = e1 * inv; gv.z = e2 * inv; gv.w = e3 * inv;
        *(float4*)&gts[rbase + b][g * 4] = gv;
    }

    float vf = 0.f, vl = 0.f;
    for (int e = 0; e < NE; ++e) {
        const unsigned short* w1e = w1t + e * (H1 * KPAD);
        #pragma unroll
        for (int nt = 0; nt < 8; ++nt) {
            f32x4 acc = {0.f, 0.f, 0.f, 0.f};
            #pragma unroll
            for (int s = 0; s < 5; ++s) {
                bf16x8 af = *(const bf16x8*)(w1e + (nt * 16 + b) * KPAD + 32 * s + 8 * g);
                acc = __builtin_amdgcn_mfma_f32_16x16x32_bf16(af, xf[s], acc, 0, 0, 0);
            }
            const float4 b1v = *(const float4*)(b1 + e * H1 + nt * 16 + 4 * g);
            unsigned lo = (unsigned)f2bf(fmaxf(acc[0] + b1v.x, 0.f)) |
                          ((unsigned)f2bf(fmaxf(acc[1] + b1v.y, 0.f)) << 16);
            unsigned hi = (unsigned)f2bf(fmaxf(acc[2] + b1v.z, 0.f)) |
                          ((unsigned)f2bf(fmaxf(acc[3] + b1v.w, 0.f)) << 16);
            uint2 hv; hv.x = lo; hv.y = hi;
            *(uint2*)&hs[rbase + b][nt * 16 + 4 * g] = hv;
        }

        bf16x8 hf[4];
        #pragma unroll
        for (int s = 0; s < 4; ++s)
            hf[s] = *(const bf16x8*)&hs[rbase + b][32 * s + 8 * g];

        float gf = gts[rbase + b][e];
        float gl = gts[rbase + b][4 + e];
        const unsigned short* w2e = w2t + e * (H2 * H1);
        #pragma unroll
        for (int ot = 0; ot < 4; ++ot) {
            f32x4 acc = {0.f, 0.f, 0.f, 0.f};
            #pragma unroll
            for (int s = 0; s < 4; ++s) {
                bf16x8 af = *(const bf16x8*)(w2e + (ot * 16 + b) * H1 + 32 * s + 8 * g);
                acc = __builtin_amdgcn_mfma_f32_16x16x32_bf16(af, hf[s], acc, 0, 0, 0);
            }
            const float4 b2v = *(const float4*)(b2 + e * H2 + ot * 16 + 4 * g);
            const float4 fwv = *(const float4*)(fW + ot * 16 + 4 * g);
            const float4 lwv = *(const float4*)(lW + ot * 16 + 4 * g);
            float o0 = fmaxf(acc[0] + b2v.x, 0.f);
            float o1 = fmaxf(acc[1] + b2v.y, 0.f);
            float o2 = fmaxf(acc[2] + b2v.z, 0.f);
            float o3 = fmaxf(acc[3] + b2v.w, 0.f);
            vf += gf * (o0 * fwv.x + o1 * fwv.y + o2 * fwv.z + o3 * fwv.w);
            vl += gl * (o0 * lwv.x + o1 * lwv.y + o2 * lwv.z + o3 * lwv.w);
        }
    }

    vf += __shfl_xor(vf, 16); vf += __shfl_xor(vf, 32);
    vl += __shfl_xor(vl, 16); vl += __shfl_xor(vl, 32);
    if (g == 0) {
        int r = grow0 + b;
        out[r]      = 1.f / (1.f + expf(-(vf + fb[0])));
        out[NB + r] = 1.f / (1.f + expf(-(vl + lb[0])));
    }
}

// ============================================================================

extern "C" void kernel_launch(void* const* d_in, const int* in_sizes, int n_in,
                              void* d_out, int out_size, void* d_ws, size_t ws_size,
                              hipStream_t stream) {
    const int*   sparse = (const int*)  d_in[0];
    const float* dense  = (const float*)d_in[1];
    const float* emb    = (const float*)d_in[2];
    const float* W1     = (const float*)d_in[3];
    const float* b1     = (const float*)d_in[4];
    const float* W2     = (const float*)d_in[5];
    const float* b2     = (const float*)d_in[6];
    const float* gfW    = (const float*)d_in[7];
    const float* gfb    = (const float*)d_in[8];
    const float* glW    = (const float*)d_in[9];
    const float* glb    = (const float*)d_in[10];
    const float* fW     = (const float*)d_in[11];
    const float* fb     = (const float*)d_in[12];
    const float* lW     = (const float*)d_in[13];
    const float* lb     = (const float*)d_in[14];

    const size_t XG_BYTES = (size_t)NB * KPAD * 2;            // 20,971,520
    const size_t NEED = XG_BYTES + (size_t)NWE * 2;           // ~21.2 MB

    if (ws_size >= NEED) {
        unsigned short* xg  = (unsigned short*)d_ws;
        unsigned short* w1p = (unsigned short*)((char*)d_ws + XG_BYTES);
        unsigned short* w2p = (unsigned short*)((char*)d_ws + XG_BYTES + (size_t)E1 * 2);
        unsigned short* gwp = (unsigned short*)((char*)d_ws + XG_BYTES + (size_t)(E1 + E2) * 2);

        gather_pack<<<GBLKS + PBLKS, 256, 0, stream>>>(
            sparse, dense, emb, W1, W2, gfW, glW, w1p, w2p, gwp, xg);
        mmoe7<<<NB / 128, 256, 0, stream>>>(xg, w1p, b1, w2p, b2, gwp,
                                            gfb, glb, fW, fb, lW, lb,
                                            (float*)d_out);
    } else {
        unsigned short* w1t = (unsigned short*)d_ws;
        unsigned short* w2t = (unsigned short*)((char*)d_ws + 163840);
        unsigned short* gwc = (unsigned short*)((char*)d_ws + 229376);

        int tot = 4*128*160 + 4*64*128 + 16*160;
        preproc<<<(tot + 255) / 256, 256, 0, stream>>>(W1, W2, gfW, glW, w1t, w2t, gwc);
        mmoe_mfma<<<NB / 64, 256, 0, stream>>>(sparse, dense, emb,
                                               w1t, b1, w2t, b2, gwc,
                                               gfb, glb, fW, fb, lW, lb,
                                               (float*)d_out);
    }
}